// Round 1
// 101.225 us; speedup vs baseline: 1.0668x; 1.0668x over previous
//
#include <hip/hip_runtime.h>
#include <math.h>

typedef float f32x4 __attribute__((ext_vector_type(4)));
typedef __bf16 bf16x8 __attribute__((ext_vector_type(8)));
typedef unsigned short u16x8 __attribute__((ext_vector_type(8)));

__device__ __forceinline__ unsigned short f2bf(float f) {
    union { float f; unsigned int u; } v; v.f = f;
    unsigned int u = v.u;
    return (unsigned short)((u + 0x7fffu + ((u >> 16) & 1u)) >> 16);  // RNE
}
__device__ __forceinline__ float bf_lo(unsigned int d) {
    union { unsigned int u; float f; } v; v.u = d << 16; return v.f;
}
__device__ __forceinline__ float bf_hi(unsigned int d) {
    union { unsigned int u; float f; } v; v.u = d & 0xffff0000u; return v.f;
}
__device__ __forceinline__ float sigmoidf_(float v) {
    return 1.f / (1.f + __expf(-v));
}

// ---------------------------------------------------------------------------
// Kernel 1: fused convert + MFMA bf16 GEMM + x->bf16 conversion.
//  left  (t<32):  A = x^T tile, B = W[e][0:256]
//                 -> LpT[b][i>>2][e][i&3] = C + b_lin[e]   (fp32, TRANSPOSED
//                    i-tile-blocked layout: attn reads 4 i-values per e as one
//                    uniform 16B scalar load, consecutive e are contiguous)
//  right (32<=t<64): A = W[e][256:512], B = x^T tile
//                 -> R2[b][(e>>3)*2048 + j*8 + (e&7)] = bf16(C)
//  conv  (t>=64): xbf[b][w][j] = bf16(x[b][w][j])  (32 blocks per b)
// ---------------------------------------------------------------------------
__global__ __launch_bounds__(256) void mfma_gemm_kernel(
    const float* __restrict__ x,      // (8,256,256) x[b][w][k]
    const float* __restrict__ W,      // (512,512)
    const float* __restrict__ b_lin,  // (512)
    float* __restrict__ LpT,          // (8,64,512,4) fp32  L^T blocked
    unsigned short* __restrict__ R2,  // (8, 512e x 256j packed)
    unsigned short* __restrict__ xbf) // (8,256,256) bf16
{
    const int b = blockIdx.y;
    const int t = blockIdx.x;

    if (t >= 64) {   // ---- x -> bf16 straight conversion
        const int idx = b * 65536 + (t - 64) * 2048 + threadIdx.x * 8;
        const float4 v0 = *(const float4*)(x + idx);
        const float4 v1 = *(const float4*)(x + idx + 4);
        u16x8 o;
        o[0] = f2bf(v0.x); o[1] = f2bf(v0.y); o[2] = f2bf(v0.z); o[3] = f2bf(v0.w);
        o[4] = f2bf(v1.x); o[5] = f2bf(v1.y); o[6] = f2bf(v1.z); o[7] = f2bf(v1.w);
        *(u16x8*)(xbf + idx) = o;
        return;
    }

    const bool left = (t < 32);
    int m0, n0;
    if (left) { m0 = (t >> 3) * 64; n0 = (t & 7) * 64; }
    else      { const int tt = t - 32; m0 = (tt >> 2) * 64; n0 = (tt & 3) * 64; }

    __shared__ unsigned short As[64][72];
    __shared__ unsigned short Bs[64][72];

    unsigned short (*Ts)[72] = left ? As : Bs;   // x^T tile
    unsigned short (*Ds)[72] = left ? Bs : As;   // W tile
    const int cbase = left ? m0 : n0;            // x column base (k or j)
    const int rbase = left ? n0 : m0;            // W row base (e)
    const int coff  = left ? 0 : 256;            // W column offset

    const int tid  = threadIdx.x;
    const int wv   = tid >> 6;
    const int lane = tid & 63;
    const int wy = wv >> 1, wx = wv & 1;
    const int lr = lane & 15;
    const int lk = lane >> 4;

    const float* xb = x + b * 65536;

    f32x4 acc[2][2];
    #pragma unroll
    for (int i = 0; i < 2; i++)
        #pragma unroll
        for (int jj = 0; jj < 2; jj++) acc[i][jj] = (f32x4){0.f, 0.f, 0.f, 0.f};

    const int wl = tid >> 4;         // 0..15
    const int kg = tid & 15;         // 0..15
    const int dr = tid >> 2;         // 0..63
    const int dc = (tid & 3) * 16;

    for (int k0 = 0; k0 < 256; k0 += 64) {
        #pragma unroll
        for (int p = 0; p < 4; p++) {
            const int w = wl + 16 * p;
            const float4 v = *(const float4*)(xb + (k0 + w) * 256 + cbase + kg * 4);
            Ts[kg * 4 + 0][w] = f2bf(v.x);
            Ts[kg * 4 + 1][w] = f2bf(v.y);
            Ts[kg * 4 + 2][w] = f2bf(v.z);
            Ts[kg * 4 + 3][w] = f2bf(v.w);
        }
        {
            const float* src = W + (rbase + dr) * 512 + coff + k0 + dc;
            const float4 v0 = *(const float4*)(src);
            const float4 v1 = *(const float4*)(src + 4);
            const float4 v2 = *(const float4*)(src + 8);
            const float4 v3 = *(const float4*)(src + 12);
            u16x8 o0, o1;
            o0[0] = f2bf(v0.x); o0[1] = f2bf(v0.y); o0[2] = f2bf(v0.z); o0[3] = f2bf(v0.w);
            o0[4] = f2bf(v1.x); o0[5] = f2bf(v1.y); o0[6] = f2bf(v1.z); o0[7] = f2bf(v1.w);
            o1[0] = f2bf(v2.x); o1[1] = f2bf(v2.y); o1[2] = f2bf(v2.z); o1[3] = f2bf(v2.w);
            o1[4] = f2bf(v3.x); o1[5] = f2bf(v3.y); o1[6] = f2bf(v3.z); o1[7] = f2bf(v3.w);
            *(u16x8*)&Ds[dr][dc]     = o0;
            *(u16x8*)&Ds[dr][dc + 8] = o1;
        }
        __syncthreads();
        #pragma unroll
        for (int kk = 0; kk < 64; kk += 32) {
            const bf16x8 a0 = *(const bf16x8*)&As[wy * 32 + lr][kk + lk * 8];
            const bf16x8 a1 = *(const bf16x8*)&As[wy * 32 + 16 + lr][kk + lk * 8];
            const bf16x8 b0 = *(const bf16x8*)&Bs[wx * 32 + lr][kk + lk * 8];
            const bf16x8 b1 = *(const bf16x8*)&Bs[wx * 32 + 16 + lr][kk + lk * 8];
            acc[0][0] = __builtin_amdgcn_mfma_f32_16x16x32_bf16(a0, b0, acc[0][0], 0, 0, 0);
            acc[0][1] = __builtin_amdgcn_mfma_f32_16x16x32_bf16(a0, b1, acc[0][1], 0, 0, 0);
            acc[1][0] = __builtin_amdgcn_mfma_f32_16x16x32_bf16(a1, b0, acc[1][0], 0, 0, 0);
            acc[1][1] = __builtin_amdgcn_mfma_f32_16x16x32_bf16(a1, b1, acc[1][1], 0, 0, 0);
        }
        __syncthreads();
    }

    // C/D layout: col = lane&15, row = (lane>>4)*4 + reg
    if (left) {
        #pragma unroll
        for (int mi = 0; mi < 2; mi++) {
            #pragma unroll
            for (int ni = 0; ni < 2; ni++) {
                const int row = m0 + wy * 32 + mi * 16 + lk * 4;   // i (=k)
                const int col = n0 + wx * 32 + ni * 16 + lr;       // e
                const float bl = b_lin[col];
                float4 o;
                o.x = acc[mi][ni][0] + bl;
                o.y = acc[mi][ni][1] + bl;
                o.z = acc[mi][ni][2] + bl;
                o.w = acc[mi][ni][3] + bl;
                // LpT[b][row>>2][col][0..3] — 16 lanes hit consecutive e =
                // 256B contiguous segments (coalesced)
                *(float4*)(LpT + b * 131072 + (row >> 2) * 2048 + col * 4) = o;
            }
        }
    } else {
        unsigned short* R2b = R2 + b * 131072;
        #pragma unroll
        for (int mi = 0; mi < 2; mi++) {
            #pragma unroll
            for (int ni = 0; ni < 2; ni++) {
                const int row = m0 + wy * 32 + mi * 16 + lk * 4;   // e base (4)
                const int col = n0 + wx * 32 + ni * 16 + lr;       // j
                ushort4 o;
                o.x = f2bf(acc[mi][ni][0]);
                o.y = f2bf(acc[mi][ni][1]);
                o.z = f2bf(acc[mi][ni][2]);
                o.w = f2bf(acc[mi][ni][3]);
                *(ushort4*)(R2b + (row >> 3) * 2048 + col * 8 + (row & 7)) = o;
            }
        }
    }
}

// ---------------------------------------------------------------------------
// Kernel 2: score + softmax + MFMA matvec + sigmoid + T-store.
// grid 512 = (i-tile of 4) x (b = blk&7, XCD-local); 1024 thr = 256 j x 4 e-q.
// 16 waves/block, 2 blocks/CU -> 32 waves/CU (100% occupancy ceiling,
// __launch_bounds__(1024,8) caps VGPR at 64 to guarantee residency).
// L and a are read with WAVE-UNIFORM addresses (blockIdx + readfirstlane(ehq)
// + loop counter only) from the blocked-transposed LpT -> compiler emits
// s_load broadcasts through the scalar cache: zero LDS staging, zero bank
// conflicts on the score path.
// score[i][j] = 0.6*(uL[i]+uR[j]) + 0.4*sum_e a[e]*|L[i,e]+R[e,j]| + bias
// ---------------------------------------------------------------------------
__global__ __launch_bounds__(1024, 8) void attn_kernel(
    const unsigned short* __restrict__ xbf,   // (8,256,256) bf16 x[b][w][j]
    const float* __restrict__ LpT,            // (8,64,512,4) fp32, b_lin folded
    const unsigned int* __restrict__ R2u,     // packed bf16 pairs
    const float* __restrict__ a,              // (512)
    const float* __restrict__ bias,           // (256,256)
    float* __restrict__ out)                  // (8,256,256)
{
    const int b     = blockIdx.x & 7;
    const int itile = blockIdx.x >> 3;        // 0..63
    const int i0    = itile * 4;
    const int tid   = threadIdx.x;
    const int j     = tid & 255;
    const int wv    = tid >> 6;               // 0..15
    const int lane  = tid & 63;

    __shared__ float acc2P[4][4][256];        // 16 KB  [e-quarter][i][j]
    __shared__ float rgp[4][256];             // 4 KB   [e-quarter][j]
    __shared__ float u15p[8][4];
    __shared__ float u15s[4];
    __shared__ unsigned short atbf[16 * 264]; // 8.25 KB (rows 4..15 unused)

    // wave-uniform e-quarter index (readfirstlane -> SGPR -> scalar loads)
    const int ehq = __builtin_amdgcn_readfirstlane(tid >> 8);  // 0..3

    // ---- uL partials: waves 0..7, e = tid; fully coalesced float4 loads
    if (tid < 512) {
        const float4 lv = *(const float4*)(LpT + b * 131072 + itile * 2048 + tid * 4);
        const float ae = a[tid];
        float p0 = ae * lv.x, p1 = ae * lv.y, p2 = ae * lv.z, p3 = ae * lv.w;
        #pragma unroll
        for (int off = 32; off; off >>= 1) {
            p0 += __shfl_xor(p0, off);
            p1 += __shfl_xor(p1, off);
            p2 += __shfl_xor(p2, off);
            p3 += __shfl_xor(p3, off);
        }
        if (lane == 0) {
            u15p[wv][0] = p0; u15p[wv][1] = p1;
            u15p[wv][2] = p2; u15p[wv][3] = p3;
        }
    }
    __syncthreads();
    if (tid < 4) {
        float s = 0.f;
        #pragma unroll
        for (int q = 0; q < 8; q++) s += u15p[q][tid];
        u15s[tid] = 0.6f * s;   // read only after the score barrier below
    }

    // ---- score: 128 e per thread (e-quarter), 4 i rows via uniform s_loads
    const float* Lq = LpT + b * 131072 + itile * 2048 + ehq * 512;  // [e_loc][4]
    const float* aq = a + ehq * 128;
    const uint4* Rq = (const uint4*)(R2u + b * 65536) + (ehq * 16) * 256 + j;

    float acc0 = 0.f, acc1 = 0.f, acc2 = 0.f, acc3 = 0.f, rsum = 0.f;

    uint4 cur = Rq[0];
    #pragma unroll 2
    for (int tk = 0; tk < 16; tk++) {
        uint4 nxt;
        if (tk < 15) nxt = Rq[(tk + 1) * 256];
        float r[8];
        r[0] = bf_lo(cur.x); r[1] = bf_hi(cur.x);
        r[2] = bf_lo(cur.y); r[3] = bf_hi(cur.y);
        r[4] = bf_lo(cur.z); r[5] = bf_hi(cur.z);
        r[6] = bf_lo(cur.w); r[7] = bf_hi(cur.w);
        #pragma unroll
        for (int q2 = 0; q2 < 2; q2++) {
            const float4 av4 = *(const float4*)(aq + tk * 8 + q2 * 4);
            #pragma unroll
            for (int s = 0; s < 4; s++) {
                const int e = tk * 8 + q2 * 4 + s;      // local e, 0..127
                const float4 lv = *(const float4*)(Lq + e * 4);  // uniform 16B
                const float ae = ((const float*)&av4)[s];
                const float rv = r[q2 * 4 + s];
                rsum = fmaf(ae, rv, rsum);
                acc0 = fmaf(ae, fabsf(lv.x + rv), acc0);
                acc1 = fmaf(ae, fabsf(lv.y + rv), acc1);
                acc2 = fmaf(ae, fabsf(lv.z + rv), acc2);
                acc3 = fmaf(ae, fabsf(lv.w + rv), acc3);
            }
        }
        cur = nxt;
    }
    acc2P[ehq][0][j] = acc0;
    acc2P[ehq][1][j] = acc1;
    acc2P[ehq][2][j] = acc2;
    acc2P[ehq][3][j] = acc3;
    rgp[ehq][j] = rsum;
    __syncthreads();

    // ---- softmax (combine folded in): wave i (wv<4) -> row i
    if (wv < 4) {
        const int i = wv;
        const float u15 = u15s[i];
        float v[4];
        float m = -1e30f;
        #pragma unroll
        for (int u = 0; u < 4; u++) {
            const int jj = lane + 64 * u;
            const float uR = rgp[0][jj] + rgp[1][jj] + rgp[2][jj] + rgp[3][jj];
            const float ab = acc2P[0][i][jj] + acc2P[1][i][jj]
                           + acc2P[2][i][jj] + acc2P[3][i][jj];
            v[u] = u15 + 0.6f * uR + 0.4f * ab + bias[(i0 + i) * 256 + jj];
            m = fmaxf(m, v[u]);
        }
        #pragma unroll
        for (int off = 32; off; off >>= 1) m = fmaxf(m, __shfl_xor(m, off));
        float ssum = 0.f;
        #pragma unroll
        for (int u = 0; u < 4; u++) { v[u] = __expf(v[u] - m); ssum += v[u]; }
        #pragma unroll
        for (int off = 32; off; off >>= 1) ssum += __shfl_xor(ssum, off);
        const float inv = 1.f / ssum;
        #pragma unroll
        for (int u = 0; u < 4; u++)
            atbf[i * 264 + lane + 64 * u] = f2bf(v[u] * inv);
    }
    __syncthreads();

    // ---- matvec via MFMA: D[i][w] = sum_j attn[i][j] * x[b][w][j]
    // 16 waves; wave wv handles w-tile wv. A rows 4..15 are garbage LDS but
    // only pollute D rows 4..15, which are never stored (lk==0 only).
    // B comes straight from precomputed bf16 xbf — no f2bf in this kernel.
    {
        const int lr = lane & 15;
        const int lk = lane >> 4;
        f32x4 hacc = (f32x4){0.f, 0.f, 0.f, 0.f};
        const unsigned short* xw = xbf + b * 65536 + (wv * 16 + lr) * 256;
        #pragma unroll
        for (int kt = 0; kt < 8; kt++) {
            const bf16x8 av = *(const bf16x8*)&atbf[lr * 264 + kt * 32 + lk * 8];
            const bf16x8 bv = *(const bf16x8*)(xw + kt * 32 + lk * 8);
            hacc = __builtin_amdgcn_mfma_f32_16x16x32_bf16(av, bv, hacc, 0, 0, 0);
        }
        if (lk == 0) {
            float4 o;
            o.x = sigmoidf_(hacc[0]);
            o.y = sigmoidf_(hacc[1]);
            o.z = sigmoidf_(hacc[2]);
            o.w = sigmoidf_(hacc[3]);
            *(float4*)(out + b * 65536 + (wv * 16 + lr) * 256 + i0) = o;
        }
    }
}

extern "C" void kernel_launch(void* const* d_in, const int* in_sizes, int n_in,
                              void* d_out, int out_size, void* d_ws, size_t ws_size,
                              hipStream_t stream) {
    const float* x     = (const float*)d_in[0];
    const float* W     = (const float*)d_in[1];
    const float* b_lin = (const float*)d_in[2];
    const float* a     = (const float*)d_in[3];
    const float* bias  = (const float*)d_in[4];
    float* out = (float*)d_out;

    char* ws = (char*)d_ws;
    float*          LpT = (float*)ws;                          // 4 MB
    unsigned short* R2  = (unsigned short*)(ws + (4 << 20));   // 2 MB
    unsigned short* xbf = (unsigned short*)(ws + (6 << 20));   // 1 MB

    mfma_gemm_kernel<<<dim3(96, 8), 256, 0, stream>>>(x, W, b_lin, LpT, R2, xbf);
    attn_kernel<<<512, 1024, 0, stream>>>(xbf, LpT, (const unsigned int*)R2, a, bias, out);
}